// Round 5
// baseline (318.887 us; speedup 1.0000x reference)
//
#include <hip/hip_runtime.h>
#include <hip/hip_bf16.h>

#define NEG_SLOPE 0.2f
#define LOG2E 1.4426950408889634f
#define BSH 9                    // 512 dst nodes per bucket
#define BW  (1 << BSH)
#define CH  4096                 // edges per partition round
#define PGRID 256                // workgroups for A0/A1

typedef short short8 __attribute__((ext_vector_type(8)));
typedef float f32x4 __attribute__((ext_vector_type(4)));

// ================= radix CSR build (no global atomics) =================

// A0: per-round bucket histogram. H[r*NBK + b] = #edges of round r in bucket b.
__global__ __launch_bounds__(256) void bucket_hist_kernel(
    const int* __restrict__ adj, int* __restrict__ H, int E, int N, int R, int NBK)
{
    __shared__ int hist[256];
    const int t = threadIdx.x;
    const int ET = E + N;
    for (int r = blockIdx.x; r < R; r += gridDim.x) {
        hist[t] = 0;
        __syncthreads();
        int base = r * CH;
        for (int i = 0; i < CH / 256; ++i) {
            int e = base + i * 256 + t;
            if (e >= ET) break;
            int d = (e < E) ? adj[E + e] : (e - E);
            atomicAdd(&hist[d >> BSH], 1);
        }
        __syncthreads();
        if (t < NBK) H[r * NBK + t] = hist[t];
        __syncthreads();
    }
}

// Per-bucket scan over rounds (196 blocks in parallel):
// S2[r][b] = sum_{r'<r} H[r'][b]  (within-bucket prefix), tot[b] = bucket total.
__global__ __launch_bounds__(256) void scan_rounds_kernel(
    const int* __restrict__ H, int* __restrict__ S2, int* __restrict__ tot,
    int R, int NBK)
{
    __shared__ int part[256];
    const int b = blockIdx.x;
    const int t = threadIdx.x;
    const int C = (R + 255) / 256;
    int r0 = t * C, r1 = min(R, r0 + C);
    int s = 0;
    for (int r = r0; r < r1; ++r) s += H[r * NBK + b];
    part[t] = s;
    __syncthreads();
    for (int off = 1; off < 256; off <<= 1) {
        int v = (t >= off) ? part[t - off] : 0;
        __syncthreads();
        part[t] += v;
        __syncthreads();
    }
    int run = (t > 0) ? part[t - 1] : 0;
    for (int r = r0; r < r1; ++r) {
        int h = H[r * NBK + b];
        S2[r * NBK + b] = run;
        run += h;
    }
    if (t == 255) tot[b] = part[255];
}

// Exclusive scan of bucket totals -> base[b]. One block; NBK <= 256.
// Also zeroes the 256-bin degree histogram for the later degree sort.
__global__ __launch_bounds__(256) void scan_tot_kernel(
    const int* __restrict__ tot, int* __restrict__ base, int NBK,
    int* __restrict__ gh)
{
    __shared__ int s[256];
    int t = threadIdx.x;
    gh[t] = 0;
    int v = (t < NBK) ? tot[t] : 0;
    s[t] = v;
    __syncthreads();
    for (int off = 1; off < 256; off <<= 1) {
        int u = (t >= off) ? s[t - off] : 0;
        __syncthreads();
        s[t] += u;
        __syncthreads();
    }
    if (t < NBK) base[t] = s[t] - v;
}

// A1: scatter edges into bucket-grouped pbuf at precomputed offsets.
// pbuf entry = (src << BSH) | (dst & (BW-1)).  src < 2^17, fits in 23+9 bits.
__global__ __launch_bounds__(256) void partition_kernel(
    const int* __restrict__ adj, const int* __restrict__ S2,
    const int* __restrict__ base, int* __restrict__ pbuf,
    int E, int N, int R, int NBK)
{
    __shared__ int lcur[256];
    const int t = threadIdx.x;
    const int ET = E + N;
    for (int r = blockIdx.x; r < R; r += gridDim.x) {
        if (t < NBK) lcur[t] = base[t] + S2[r * NBK + t];
        __syncthreads();
        int b0 = r * CH;
        for (int i = 0; i < CH / 256; ++i) {
            int e = b0 + i * 256 + t;
            if (e >= ET) break;
            int s, d;
            if (e < E) { d = adj[E + e]; s = adj[e]; }
            else       { s = d = e - E; }
            int b = d >> BSH;
            int pos = atomicAdd(&lcur[b], 1);
            pbuf[pos] = (s << BSH) | (d & (BW - 1));
        }
        __syncthreads();
    }
}

// B: one WG per bucket. LDS hist over 512 local nodes + LDS scan ->
// row_ptr window AND node-grouped col_idx, all inside a ~35KB L2-local window.
__global__ __launch_bounds__(256) void csr_build_kernel(
    const int* __restrict__ base, const int* __restrict__ tot,
    const int* __restrict__ pbuf,
    int* __restrict__ row_ptr, int* __restrict__ col_idx, int E, int N, int NBK)
{
    __shared__ int offA[BW];
    __shared__ int lcur[BW];
    const int b = blockIdx.x;
    const int t = threadIdx.x;
    const int node0 = b << BSH;
    const int nn = min(BW, N - node0);
    const int ET = E + N;
    const int segbeg = base[b];
    const int segend = segbeg + tot[b];

    offA[t] = 0; offA[t + 256] = 0;
    __syncthreads();
    for (int i = segbeg + t; i < segend; i += 256)
        atomicAdd(&offA[pbuf[i] & (BW - 1)], 1);
    __syncthreads();
    // inclusive Hillis-Steele scan over 512 elements (2 per thread)
    for (int off = 1; off < BW; off <<= 1) {
        int i1 = t + 256;
        int v0 = (t >= off) ? offA[t - off] : 0;
        int v1 = (i1 >= off) ? offA[i1 - off] : 0;
        __syncthreads();
        offA[t] += v0; offA[i1] += v1;
        __syncthreads();
    }
    if (t < nn) {
        int ex = t ? offA[t - 1] : 0;
        row_ptr[node0 + t] = segbeg + ex;
        lcur[t] = segbeg + ex;
    }
    int i2 = t + 256;
    if (i2 < nn) {
        int ex = offA[i2 - 1];
        row_ptr[node0 + i2] = segbeg + ex;
        lcur[i2] = segbeg + ex;
    }
    if (b == NBK - 1 && t == 0) row_ptr[N] = ET;
    __syncthreads();
    for (int i = segbeg + t; i < segend; i += 256) {
        int p = pbuf[i];
        int pos = atomicAdd(&lcur[p & (BW - 1)], 1);
        col_idx[pos] = p >> BSH;
    }
}

// ================= degree-binned node permutation =================
// Counting sort of nodes by degree (clamped to 255) so the aggregate's
// 8 nodes-per-wave have near-uniform degree -> exec-mask waste ~0.

__global__ __launch_bounds__(256) void deg_hist_kernel(
    const int* __restrict__ row_ptr, int* __restrict__ gh, int N)
{
    __shared__ int lh[256];
    const int t = threadIdx.x;
    lh[t] = 0;
    __syncthreads();
    for (int n = blockIdx.x * 256 + t; n < N; n += gridDim.x * 256)
        atomicAdd(&lh[min(row_ptr[n + 1] - row_ptr[n], 255)], 1);
    __syncthreads();
    if (lh[t]) atomicAdd(&gh[t], lh[t]);
}

__global__ __launch_bounds__(256) void deg_scan_kernel(
    const int* __restrict__ gh, int* __restrict__ gcur)
{
    __shared__ int s[256];
    int t = threadIdx.x;
    int v = gh[t];
    s[t] = v;
    __syncthreads();
    for (int off = 1; off < 256; off <<= 1) {
        int u = (t >= off) ? s[t - off] : 0;
        __syncthreads();
        s[t] += u;
        __syncthreads();
    }
    gcur[t] = s[t] - v;
}

__global__ __launch_bounds__(256) void deg_scatter_kernel(
    const int* __restrict__ row_ptr, int* __restrict__ gcur,
    int* __restrict__ perm, int N)
{
    __shared__ int lh[256], lcur[256];
    const int t = threadIdx.x;
    const int n0 = blockIdx.x * 2048;
    const int n1 = min(N, n0 + 2048);
    lh[t] = 0;
    __syncthreads();
    for (int n = n0 + t; n < n1; n += 256)
        atomicAdd(&lh[min(row_ptr[n + 1] - row_ptr[n], 255)], 1);
    __syncthreads();
    lcur[t] = lh[t] ? atomicAdd(&gcur[t], lh[t]) : 0;
    __syncthreads();
    for (int n = n0 + t; n < n1; n += 256) {
        int pos = atomicAdd(&lcur[min(row_ptr[n + 1] - row_ptr[n], 255)], 1);
        perm[pos] = n;
    }
}

// ================= dense pieces =================

__device__ __forceinline__ unsigned short f2bf(float f)
{
    union { __hip_bfloat16 b; unsigned short u; } v;
    v.b = __float2bfloat16(f);
    return v.u;
}

// Pre-pack W into MFMA B-fragment order, bf16.
// Fragment f = s*4 + t  (s = K-step of 32, t = 16-col tile).
// lane l (0..63), elem i (0..7):  k = 32*s + 8*(l/16) + i,  n = 16*t + (l%16).
__global__ __launch_bounds__(256) void prep_wfrag_kernel(
    const float* __restrict__ W, unsigned short* __restrict__ wf, int K)
{
    int total = K * 64;                  // (K/32)*4 frags * 64 lanes * 8 elems
    int idx = blockIdx.x * 256 + threadIdx.x;
    if (idx >= total) return;
    int i = idx & 7;
    int l = (idx >> 3) & 63;
    int f = idx >> 9;
    int s = f >> 2, tt = f & 3;
    int k = 32 * s + 8 * (l >> 4) + i;
    int n = 16 * tt + (l & 15);
    wf[idx] = f2bf(W[k * 64 + n]);
}

// MFMA GEMM + alpha:  h = bf16(X @ W); as[n] = (h . a_src)*log2e; ad likewise.
// 4 waves/block, each wave owns 16 rows x 64 cols (4 col-tiles of 16x16 MFMA).
// X is split hi+lo bf16 (2 MFMAs per tile) -> A-side error ~2^-16 relative.
// as_/ad_ are pre-scaled by log2(e) so the aggregate can use exp2 directly
// (leaky_relu is positively homogeneous: exp(leaky(x)) == exp2(leaky(x*log2e))).
template<int K>
__global__ __launch_bounds__(256) void gemm_alpha_mfma(
    const float* __restrict__ X, const unsigned short* __restrict__ wf,
    const float* __restrict__ a_src, const float* __restrict__ a_dst,
    __hip_bfloat16* __restrict__ h, float* __restrict__ as_, float* __restrict__ ad_,
    int N, int nChunks)
{
    constexpr int S = K / 32;
    const int t = threadIdx.x;
    const int wave = t >> 6, lane = t & 63;
    const int g = lane >> 4, c = lane & 15;

    // B fragments: S*4 frags, 8 bf16 each (4 VGPRs) -> coalesced 16B loads
    short8 bf[S * 4];
#pragma unroll
    for (int f = 0; f < S * 4; ++f)
        bf[f] = *(const short8*)(wf + ((size_t)(f * 64 + lane)) * 8);

    float asr[4], adr[4];
#pragma unroll
    for (int tt = 0; tt < 4; ++tt) {
        asr[tt] = a_src[16 * tt + c];
        adr[tt] = a_dst[16 * tt + c];
    }

    for (int chunk = blockIdx.x; chunk < nChunks; chunk += gridDim.x) {
        const int r0 = chunk * 64 + wave * 16;
        const int arow = r0 + c;                 // row this lane loads for A
        const bool rv = arow < N;
        const float* xr = X + (size_t)arow * K;

        f32x4 acc[4];
#pragma unroll
        for (int tt = 0; tt < 4; ++tt) acc[tt] = (f32x4){0.f, 0.f, 0.f, 0.f};

#pragma unroll
        for (int s = 0; s < S; ++s) {
            // lane reads X[arow][32s + 8g .. 32s + 8g + 7]
            float4 x0 = make_float4(0.f, 0.f, 0.f, 0.f);
            float4 x1 = make_float4(0.f, 0.f, 0.f, 0.f);
            if (rv) {
                const float4* p = (const float4*)(xr + 32 * s + 8 * g);
                x0 = p[0]; x1 = p[1];
            }
            float xs[8] = {x0.x, x0.y, x0.z, x0.w, x1.x, x1.y, x1.z, x1.w};
            // hi = truncate-to-bf16, lo = truncate(x - hi): exact split to ~2^-16
            union { short8 v; unsigned u[4]; } ah, al;
#pragma unroll
            for (int p2 = 0; p2 < 4; ++p2) {
                unsigned u0 = __float_as_uint(xs[2 * p2]);
                unsigned u1 = __float_as_uint(xs[2 * p2 + 1]);
                ah.u[p2] = (u0 >> 16) | (u1 & 0xffff0000u);
                float h0 = __uint_as_float(u0 & 0xffff0000u);
                float h1 = __uint_as_float(u1 & 0xffff0000u);
                unsigned l0 = __float_as_uint(xs[2 * p2] - h0);
                unsigned l1 = __float_as_uint(xs[2 * p2 + 1] - h1);
                al.u[p2] = (l0 >> 16) | (l1 & 0xffff0000u);
            }
#pragma unroll
            for (int tt = 0; tt < 4; ++tt) {
                acc[tt] = __builtin_amdgcn_mfma_f32_16x16x32_bf16(
                    ah.v, bf[s * 4 + tt], acc[tt], 0, 0, 0);
                acc[tt] = __builtin_amdgcn_mfma_f32_16x16x32_bf16(
                    al.v, bf[s * 4 + tt], acc[tt], 0, 0, 0);
            }
        }

        // epilogue: D layout col = c + 16*tt, row = r0 + 4*g + i  [measured m89/m91]
#pragma unroll
        for (int i = 0; i < 4; ++i) {
            const int ri = r0 + 4 * g + i;
            float va = 0.f, vd = 0.f;
#pragma unroll
            for (int tt = 0; tt < 4; ++tt) {
                float v = acc[tt][i];
                va += v * asr[tt];
                vd += v * adr[tt];
                if (ri < N) h[(size_t)ri * 64 + 16 * tt + c] = __float2bfloat16(v);
            }
#pragma unroll
            for (int off = 8; off >= 1; off >>= 1) {
                va += __shfl_xor(va, off, 16);
                vd += __shfl_xor(vd, off, 16);
            }
            if (c == 0 && ri < N) { as_[ri] = va * LOG2E; ad_[ri] = vd * LOG2E; }
        }
    }
}

// Fused softmax+aggregate: ONE 8-LANE SUB PER NODE (8 nodes per wave),
// processed in degree-sorted order (perm) so all 8 subs of a wave have
// near-equal trip counts -> exec-mask waste ~0.
// Each lane owns 8 fixed output dims -> acc needs NO cross-lane reduce;
// psum is computed redundantly by the sub's 8 lanes -> NO reduce either.
__global__ __launch_bounds__(256) void gat_aggregate_kernel(
    const int* __restrict__ perm,
    const int* __restrict__ row_ptr, const int* __restrict__ col_idx,
    const float* __restrict__ as_, const float* __restrict__ ad_,
    const __hip_bfloat16* __restrict__ h, const float* __restrict__ b,
    float* __restrict__ out, int N, int do_elu)
{
    const int wave = threadIdx.x >> 6, lane = threadIdx.x & 63;
    const int sub = lane >> 3, q = lane & 7;
    const int idx = blockIdx.x * 32 + wave * 8 + sub;
    if (idx >= N) return;
    const int node = perm[idx];
    const int beg = row_ptr[node], end = row_ptr[node + 1];
    const float ad = ad_[node];          // pre-scaled by log2e
    float acc[8] = {0.f, 0.f, 0.f, 0.f, 0.f, 0.f, 0.f, 0.f};
    float psum = 0.f;

    const char* cbp = (const char*)col_idx;
    const char* abp = (const char*)as_;
    const char* hbp = (const char*)h;
    const unsigned qb = (unsigned)q * 16u;

    unsigned co = (unsigned)beg * 4u;
    for (int i = beg; i < end; i += 2, co += 8u) {
        const bool v1 = (i + 1) < end;
        int s0 = *(const int*)(cbp + co);
        int s1 = *(const int*)(cbp + (v1 ? co + 4u : co));
        float x0 = *(const float*)(abp + ((unsigned)s0 << 2)) + ad;
        float x1 = *(const float*)(abp + ((unsigned)s1 << 2)) + ad;
        uint4 u0 = *(const uint4*)(hbp + (((unsigned)s0 << 7) + qb));
        uint4 u1 = *(const uint4*)(hbp + (((unsigned)s1 << 7) + qb));
        x0 = fmaxf(x0, NEG_SLOPE * x0);
        x1 = fmaxf(x1, NEG_SLOPE * x1);
        float p0 = __builtin_amdgcn_exp2f(x0);
        float p1 = v1 ? __builtin_amdgcn_exp2f(x1) : 0.f;
        psum += p0 + p1;
        unsigned w;
        w = u0.x; acc[0] += p0 * __uint_as_float(w << 16); acc[1] += p0 * __uint_as_float(w & 0xffff0000u);
        w = u0.y; acc[2] += p0 * __uint_as_float(w << 16); acc[3] += p0 * __uint_as_float(w & 0xffff0000u);
        w = u0.z; acc[4] += p0 * __uint_as_float(w << 16); acc[5] += p0 * __uint_as_float(w & 0xffff0000u);
        w = u0.w; acc[6] += p0 * __uint_as_float(w << 16); acc[7] += p0 * __uint_as_float(w & 0xffff0000u);
        w = u1.x; acc[0] += p1 * __uint_as_float(w << 16); acc[1] += p1 * __uint_as_float(w & 0xffff0000u);
        w = u1.y; acc[2] += p1 * __uint_as_float(w << 16); acc[3] += p1 * __uint_as_float(w & 0xffff0000u);
        w = u1.z; acc[4] += p1 * __uint_as_float(w << 16); acc[5] += p1 * __uint_as_float(w & 0xffff0000u);
        w = u1.w; acc[6] += p1 * __uint_as_float(w << 16); acc[7] += p1 * __uint_as_float(w & 0xffff0000u);
    }

    const float inv = 1.f / psum;
    const float* bq = b + q * 8;
    float4 b0 = *(const float4*)bq;
    float4 b1 = *(const float4*)(bq + 4);
    float v[8];
    v[0] = acc[0] * inv + b0.x; v[1] = acc[1] * inv + b0.y;
    v[2] = acc[2] * inv + b0.z; v[3] = acc[3] * inv + b0.w;
    v[4] = acc[4] * inv + b1.x; v[5] = acc[5] * inv + b1.y;
    v[6] = acc[6] * inv + b1.z; v[7] = acc[7] * inv + b1.w;
    if (do_elu) {
#pragma unroll
        for (int j = 0; j < 8; ++j)
            v[j] = v[j] > 0.f ? v[j] : (__expf(v[j]) - 1.f);
    }
    float* op = out + (size_t)node * 64 + q * 8;
    ((float4*)op)[0] = make_float4(v[0], v[1], v[2], v[3]);
    ((float4*)op)[1] = make_float4(v[4], v[5], v[6], v[7]);
}

// logits[n][c] = x[n]·cW[:,c] + cb[c]
__global__ __launch_bounds__(256) void classifier_kernel(
    const float* __restrict__ x, const float* __restrict__ cw,
    const float* __restrict__ cb, float* __restrict__ out, int N)
{
    int i = blockIdx.x * blockDim.x + threadIdx.x;
    if (i >= N * 16) return;
    int n = i >> 4, c = i & 15;
    const float4* xr = (const float4*)(x + (size_t)n * 64);
    float acc = cb[c];
#pragma unroll
    for (int j4 = 0; j4 < 16; ++j4) {
        float4 xv = xr[j4];
        acc += xv.x * cw[(j4 * 4 + 0) * 16 + c];
        acc += xv.y * cw[(j4 * 4 + 1) * 16 + c];
        acc += xv.z * cw[(j4 * 4 + 2) * 16 + c];
        acc += xv.w * cw[(j4 * 4 + 3) * 16 + c];
    }
    out[i] = acc;
}

extern "C" void kernel_launch(void* const* d_in, const int* in_sizes, int n_in,
                              void* d_out, int out_size, void* d_ws, size_t ws_size,
                              hipStream_t stream)
{
    const float* X    = (const float*)d_in[0];
    const int*   adj  = (const int*)d_in[1];
    const float* W1   = (const float*)d_in[2];
    const float* a_s1 = (const float*)d_in[3];
    const float* a_d1 = (const float*)d_in[4];
    const float* b1   = (const float*)d_in[5];
    const float* W2   = (const float*)d_in[6];
    const float* a_s2 = (const float*)d_in[7];
    const float* a_d2 = (const float*)d_in[8];
    const float* b2   = (const float*)d_in[9];
    const float* cW   = (const float*)d_in[10];
    const float* cb   = (const float*)d_in[11];

    const int N   = in_sizes[0] / 128;
    const int E   = in_sizes[1] / 2;
    const int ET  = E + N;
    const int R   = (ET + CH - 1) / CH;           // partition rounds
    const int NBK = (N + BW - 1) >> BSH;          // buckets (<=256)

    __hip_bfloat16* A = (__hip_bfloat16*)d_ws;        // h (bf16), N*64
    float* B       = (float*)(A + (size_t)N * 64);    // layer1 x, N*64 f32
    float* asb     = B + (size_t)N * 64;              // N
    float* adb     = asb + N;                         // N
    int*   row_ptr = (int*)(adb + N);                 // N+1
    int*   col_idx = row_ptr + (N + 1);               // ET
    int*   pbuf    = col_idx + ET;                    // ET
    int*   H       = pbuf + ET;                       // R*NBK
    int*   S2      = H + R * NBK;                     // R*NBK
    int*   tot     = S2 + R * NBK;                    // NBK
    int*   base    = tot + NBK;                       // NBK
    int*   perm    = base + NBK;                      // N
    int*   gh      = perm + N;                        // 256
    int*   gcur    = gh + 256;                        // 256

    // W fragment buffers alias pbuf (dead after csr_build; preps run after it)
    uintptr_t wp = ((uintptr_t)pbuf + 15) & ~(uintptr_t)15;
    unsigned short* wf1 = (unsigned short*)wp;        // 128*64 ushort = 16KB
    unsigned short* wf2 = wf1 + 128 * 64;             // 64*64 ushort = 8KB

    const int T = 256;
    const int aggBlocks  = (N + 31) / 32;
    const int nChunks    = (N + 63) / 64;
    const int gemmBlocks = nChunks < 512 ? nChunks : 512;

    // ---- radix CSR build (once, reused by both layers) ----
    bucket_hist_kernel<<<PGRID, T, 0, stream>>>(adj, H, E, N, R, NBK);
    scan_rounds_kernel<<<NBK, T, 0, stream>>>(H, S2, tot, R, NBK);
    scan_tot_kernel<<<1, T, 0, stream>>>(tot, base, NBK, gh);
    partition_kernel<<<PGRID, T, 0, stream>>>(adj, S2, base, pbuf, E, N, R, NBK);
    csr_build_kernel<<<NBK, T, 0, stream>>>(base, tot, pbuf, row_ptr, col_idx, E, N, NBK);

    // ---- degree-binned node permutation (uniform-degree waves for agg) ----
    deg_hist_kernel<<<128, T, 0, stream>>>(row_ptr, gh, N);
    deg_scan_kernel<<<1, T, 0, stream>>>(gh, gcur);
    deg_scatter_kernel<<<(N + 2047) / 2048, T, 0, stream>>>(row_ptr, gcur, perm, N);

    // ---- pack W fragments (after csr_build: pbuf space is dead now) ----
    prep_wfrag_kernel<<<(128 * 64 + 255) / 256, T, 0, stream>>>(W1, wf1, 128);
    prep_wfrag_kernel<<<(64 * 64 + 255) / 256, T, 0, stream>>>(W2, wf2, 64);

    // ---- layer 1 ----
    gemm_alpha_mfma<128><<<gemmBlocks, T, 0, stream>>>(
        X, wf1, a_s1, a_d1, A, asb, adb, N, nChunks);
    gat_aggregate_kernel<<<aggBlocks, T, 0, stream>>>(
        perm, row_ptr, col_idx, asb, adb, A, b1, B, N, 1);

    // ---- layer 2 (x written straight into d_out tail) ----
    float* out  = (float*)d_out;
    float* xout = out + (size_t)N * 16;
    gemm_alpha_mfma<64><<<gemmBlocks, T, 0, stream>>>(
        B, wf2, a_s2, a_d2, A, asb, adb, N, nChunks);
    gat_aggregate_kernel<<<aggBlocks, T, 0, stream>>>(
        perm, row_ptr, col_idx, asb, adb, A, b2, xout, N, 0);

    // ---- classifier ----
    classifier_kernel<<<(N * 16 + T - 1) / T, T, 0, stream>>>(
        xout, cW, cb, out, N);
}

// Round 6
// 313.086 us; speedup vs baseline: 1.0185x; 1.0185x over previous
//
#include <hip/hip_runtime.h>
#include <hip/hip_bf16.h>

#define NEG_SLOPE 0.2f
#define LOG2E 1.4426950408889634f
#define BSH 9                    // 512 dst nodes per bucket
#define BW  (1 << BSH)
#define CH  4096                 // edges per partition round
#define PGRID 256                // workgroups for A0/A1

typedef short short8 __attribute__((ext_vector_type(8)));
typedef float f32x4 __attribute__((ext_vector_type(4)));

// ================= radix CSR build (no global atomics) =================

// A0: per-round bucket histogram. H[r*NBK + b] = #edges of round r in bucket b.
__global__ __launch_bounds__(256) void bucket_hist_kernel(
    const int* __restrict__ adj, int* __restrict__ H, int E, int N, int R, int NBK)
{
    __shared__ int hist[256];
    const int t = threadIdx.x;
    const int ET = E + N;
    for (int r = blockIdx.x; r < R; r += gridDim.x) {
        hist[t] = 0;
        __syncthreads();
        int base = r * CH;
        for (int i = 0; i < CH / 256; ++i) {
            int e = base + i * 256 + t;
            if (e >= ET) break;
            int d = (e < E) ? adj[E + e] : (e - E);
            atomicAdd(&hist[d >> BSH], 1);
        }
        __syncthreads();
        if (t < NBK) H[r * NBK + t] = hist[t];
        __syncthreads();
    }
}

// Per-bucket scan over rounds (196 blocks in parallel):
// S2[r][b] = sum_{r'<r} H[r'][b]  (within-bucket prefix), tot[b] = bucket total.
__global__ __launch_bounds__(256) void scan_rounds_kernel(
    const int* __restrict__ H, int* __restrict__ S2, int* __restrict__ tot,
    int R, int NBK)
{
    __shared__ int part[256];
    const int b = blockIdx.x;
    const int t = threadIdx.x;
    const int C = (R + 255) / 256;
    int r0 = t * C, r1 = min(R, r0 + C);
    int s = 0;
    for (int r = r0; r < r1; ++r) s += H[r * NBK + b];
    part[t] = s;
    __syncthreads();
    for (int off = 1; off < 256; off <<= 1) {
        int v = (t >= off) ? part[t - off] : 0;
        __syncthreads();
        part[t] += v;
        __syncthreads();
    }
    int run = (t > 0) ? part[t - 1] : 0;
    for (int r = r0; r < r1; ++r) {
        int h = H[r * NBK + b];
        S2[r * NBK + b] = run;
        run += h;
    }
    if (t == 255) tot[b] = part[255];
}

// Exclusive scan of bucket totals -> base[b]. One block; NBK <= 256.
// Also zeroes the 256-bin degree histogram for the later degree sort.
__global__ __launch_bounds__(256) void scan_tot_kernel(
    const int* __restrict__ tot, int* __restrict__ base, int NBK,
    int* __restrict__ gh)
{
    __shared__ int s[256];
    int t = threadIdx.x;
    gh[t] = 0;
    int v = (t < NBK) ? tot[t] : 0;
    s[t] = v;
    __syncthreads();
    for (int off = 1; off < 256; off <<= 1) {
        int u = (t >= off) ? s[t - off] : 0;
        __syncthreads();
        s[t] += u;
        __syncthreads();
    }
    if (t < NBK) base[t] = s[t] - v;
}

// A1: scatter edges into bucket-grouped pbuf at precomputed offsets.
// pbuf entry = (src << BSH) | (dst & (BW-1)).  src < 2^17, fits in 23+9 bits.
__global__ __launch_bounds__(256) void partition_kernel(
    const int* __restrict__ adj, const int* __restrict__ S2,
    const int* __restrict__ base, int* __restrict__ pbuf,
    int E, int N, int R, int NBK)
{
    __shared__ int lcur[256];
    const int t = threadIdx.x;
    const int ET = E + N;
    for (int r = blockIdx.x; r < R; r += gridDim.x) {
        if (t < NBK) lcur[t] = base[t] + S2[r * NBK + t];
        __syncthreads();
        int b0 = r * CH;
        for (int i = 0; i < CH / 256; ++i) {
            int e = b0 + i * 256 + t;
            if (e >= ET) break;
            int s, d;
            if (e < E) { d = adj[E + e]; s = adj[e]; }
            else       { s = d = e - E; }
            int b = d >> BSH;
            int pos = atomicAdd(&lcur[b], 1);
            pbuf[pos] = (s << BSH) | (d & (BW - 1));
        }
        __syncthreads();
    }
}

// B: one WG per bucket. LDS hist over 512 local nodes + LDS scan ->
// row_ptr window AND node-grouped col_idx, all inside a ~35KB L2-local window.
__global__ __launch_bounds__(256) void csr_build_kernel(
    const int* __restrict__ base, const int* __restrict__ tot,
    const int* __restrict__ pbuf,
    int* __restrict__ row_ptr, int* __restrict__ col_idx, int E, int N, int NBK)
{
    __shared__ int offA[BW];
    __shared__ int lcur[BW];
    const int b = blockIdx.x;
    const int t = threadIdx.x;
    const int node0 = b << BSH;
    const int nn = min(BW, N - node0);
    const int ET = E + N;
    const int segbeg = base[b];
    const int segend = segbeg + tot[b];

    offA[t] = 0; offA[t + 256] = 0;
    __syncthreads();
    for (int i = segbeg + t; i < segend; i += 256)
        atomicAdd(&offA[pbuf[i] & (BW - 1)], 1);
    __syncthreads();
    // inclusive Hillis-Steele scan over 512 elements (2 per thread)
    for (int off = 1; off < BW; off <<= 1) {
        int i1 = t + 256;
        int v0 = (t >= off) ? offA[t - off] : 0;
        int v1 = (i1 >= off) ? offA[i1 - off] : 0;
        __syncthreads();
        offA[t] += v0; offA[i1] += v1;
        __syncthreads();
    }
    if (t < nn) {
        int ex = t ? offA[t - 1] : 0;
        row_ptr[node0 + t] = segbeg + ex;
        lcur[t] = segbeg + ex;
    }
    int i2 = t + 256;
    if (i2 < nn) {
        int ex = offA[i2 - 1];
        row_ptr[node0 + i2] = segbeg + ex;
        lcur[i2] = segbeg + ex;
    }
    if (b == NBK - 1 && t == 0) row_ptr[N] = ET;
    __syncthreads();
    for (int i = segbeg + t; i < segend; i += 256) {
        int p = pbuf[i];
        int pos = atomicAdd(&lcur[p & (BW - 1)], 1);
        col_idx[pos] = p >> BSH;
    }
}

// ================= degree-binned node permutation =================
// Counting sort of nodes by degree (clamped to 255) so the aggregate's
// 8 nodes-per-wave have near-uniform degree -> exec-mask waste ~0.

__global__ __launch_bounds__(256) void deg_hist_kernel(
    const int* __restrict__ row_ptr, int* __restrict__ gh, int N)
{
    __shared__ int lh[256];
    const int t = threadIdx.x;
    lh[t] = 0;
    __syncthreads();
    for (int n = blockIdx.x * 256 + t; n < N; n += gridDim.x * 256)
        atomicAdd(&lh[min(row_ptr[n + 1] - row_ptr[n], 255)], 1);
    __syncthreads();
    if (lh[t]) atomicAdd(&gh[t], lh[t]);
}

__global__ __launch_bounds__(256) void deg_scan_kernel(
    const int* __restrict__ gh, int* __restrict__ gcur)
{
    __shared__ int s[256];
    int t = threadIdx.x;
    int v = gh[t];
    s[t] = v;
    __syncthreads();
    for (int off = 1; off < 256; off <<= 1) {
        int u = (t >= off) ? s[t - off] : 0;
        __syncthreads();
        s[t] += u;
        __syncthreads();
    }
    gcur[t] = s[t] - v;
}

__global__ __launch_bounds__(256) void deg_scatter_kernel(
    const int* __restrict__ row_ptr, int* __restrict__ gcur,
    int* __restrict__ perm, int N)
{
    __shared__ int lh[256], lcur[256];
    const int t = threadIdx.x;
    const int n0 = blockIdx.x * 2048;
    const int n1 = min(N, n0 + 2048);
    lh[t] = 0;
    __syncthreads();
    for (int n = n0 + t; n < n1; n += 256)
        atomicAdd(&lh[min(row_ptr[n + 1] - row_ptr[n], 255)], 1);
    __syncthreads();
    lcur[t] = lh[t] ? atomicAdd(&gcur[t], lh[t]) : 0;
    __syncthreads();
    for (int n = n0 + t; n < n1; n += 256) {
        int pos = atomicAdd(&lcur[min(row_ptr[n + 1] - row_ptr[n], 255)], 1);
        perm[pos] = n;
    }
}

// ================= dense pieces =================

__device__ __forceinline__ unsigned short f2bf(float f)
{
    union { __hip_bfloat16 b; unsigned short u; } v;
    v.b = __float2bfloat16(f);
    return v.u;
}

// Pre-pack W into MFMA B-fragment order, bf16.
// Fragment f = s*4 + t  (s = K-step of 32, t = 16-col tile).
// lane l (0..63), elem i (0..7):  k = 32*s + 8*(l/16) + i,  n = 16*t + (l%16).
__global__ __launch_bounds__(256) void prep_wfrag_kernel(
    const float* __restrict__ W, unsigned short* __restrict__ wf, int K)
{
    int total = K * 64;                  // (K/32)*4 frags * 64 lanes * 8 elems
    int idx = blockIdx.x * 256 + threadIdx.x;
    if (idx >= total) return;
    int i = idx & 7;
    int l = (idx >> 3) & 63;
    int f = idx >> 9;
    int s = f >> 2, tt = f & 3;
    int k = 32 * s + 8 * (l >> 4) + i;
    int n = 16 * tt + (l & 15);
    wf[idx] = f2bf(W[k * 64 + n]);
}

// MFMA GEMM + alpha:  h = bf16(X @ W); as[n] = (h . a_src)*log2e; ad likewise.
// 4 waves/block, each wave owns 16 rows x 64 cols (4 col-tiles of 16x16 MFMA).
// X is split hi+lo bf16 (2 MFMAs per tile) -> A-side error ~2^-16 relative.
// as_/ad_ are pre-scaled by log2(e) so the aggregate can use exp2 directly
// (leaky_relu is positively homogeneous: exp(leaky(x)) == exp2(leaky(x*log2e))).
template<int K>
__global__ __launch_bounds__(256) void gemm_alpha_mfma(
    const float* __restrict__ X, const unsigned short* __restrict__ wf,
    const float* __restrict__ a_src, const float* __restrict__ a_dst,
    __hip_bfloat16* __restrict__ h, float* __restrict__ as_, float* __restrict__ ad_,
    int N, int nChunks)
{
    constexpr int S = K / 32;
    const int t = threadIdx.x;
    const int wave = t >> 6, lane = t & 63;
    const int g = lane >> 4, c = lane & 15;

    // B fragments: S*4 frags, 8 bf16 each (4 VGPRs) -> coalesced 16B loads
    short8 bf[S * 4];
#pragma unroll
    for (int f = 0; f < S * 4; ++f)
        bf[f] = *(const short8*)(wf + ((size_t)(f * 64 + lane)) * 8);

    float asr[4], adr[4];
#pragma unroll
    for (int tt = 0; tt < 4; ++tt) {
        asr[tt] = a_src[16 * tt + c];
        adr[tt] = a_dst[16 * tt + c];
    }

    for (int chunk = blockIdx.x; chunk < nChunks; chunk += gridDim.x) {
        const int r0 = chunk * 64 + wave * 16;
        const int arow = r0 + c;                 // row this lane loads for A
        const bool rv = arow < N;
        const float* xr = X + (size_t)arow * K;

        f32x4 acc[4];
#pragma unroll
        for (int tt = 0; tt < 4; ++tt) acc[tt] = (f32x4){0.f, 0.f, 0.f, 0.f};

#pragma unroll
        for (int s = 0; s < S; ++s) {
            // lane reads X[arow][32s + 8g .. 32s + 8g + 7]
            float4 x0 = make_float4(0.f, 0.f, 0.f, 0.f);
            float4 x1 = make_float4(0.f, 0.f, 0.f, 0.f);
            if (rv) {
                const float4* p = (const float4*)(xr + 32 * s + 8 * g);
                x0 = p[0]; x1 = p[1];
            }
            float xs[8] = {x0.x, x0.y, x0.z, x0.w, x1.x, x1.y, x1.z, x1.w};
            // hi = truncate-to-bf16, lo = truncate(x - hi): exact split to ~2^-16
            union { short8 v; unsigned u[4]; } ah, al;
#pragma unroll
            for (int p2 = 0; p2 < 4; ++p2) {
                unsigned u0 = __float_as_uint(xs[2 * p2]);
                unsigned u1 = __float_as_uint(xs[2 * p2 + 1]);
                ah.u[p2] = (u0 >> 16) | (u1 & 0xffff0000u);
                float h0 = __uint_as_float(u0 & 0xffff0000u);
                float h1 = __uint_as_float(u1 & 0xffff0000u);
                unsigned l0 = __float_as_uint(xs[2 * p2] - h0);
                unsigned l1 = __float_as_uint(xs[2 * p2 + 1] - h1);
                al.u[p2] = (l0 >> 16) | (l1 & 0xffff0000u);
            }
#pragma unroll
            for (int tt = 0; tt < 4; ++tt) {
                acc[tt] = __builtin_amdgcn_mfma_f32_16x16x32_bf16(
                    ah.v, bf[s * 4 + tt], acc[tt], 0, 0, 0);
                acc[tt] = __builtin_amdgcn_mfma_f32_16x16x32_bf16(
                    al.v, bf[s * 4 + tt], acc[tt], 0, 0, 0);
            }
        }

        // epilogue: D layout col = c + 16*tt, row = r0 + 4*g + i  [measured m89/m91]
#pragma unroll
        for (int i = 0; i < 4; ++i) {
            const int ri = r0 + 4 * g + i;
            float va = 0.f, vd = 0.f;
#pragma unroll
            for (int tt = 0; tt < 4; ++tt) {
                float v = acc[tt][i];
                va += v * asr[tt];
                vd += v * adr[tt];
                if (ri < N) h[(size_t)ri * 64 + 16 * tt + c] = __float2bfloat16(v);
            }
#pragma unroll
            for (int off = 8; off >= 1; off >>= 1) {
                va += __shfl_xor(va, off, 16);
                vd += __shfl_xor(vd, off, 16);
            }
            if (c == 0 && ri < N) { as_[ri] = va * LOG2E; ad_[ri] = vd * LOG2E; }
        }
    }
}

// Fused softmax+aggregate: ONE 8-LANE SUB PER NODE (8 nodes per wave),
// degree-sorted via perm (uniform trip counts), 4-EDGE UNROLLED WINDOWS:
// issue 4 col_idx + 4 as_ + 4 h gathers before any compute -> 4 memory
// chains in flight per wave (latency hiding), tail = masked 1-edge loop.
#define ACC8(u, p)                                                              \
    w = u.x; acc[0] += p * __uint_as_float(w << 16); acc[1] += p * __uint_as_float(w & 0xffff0000u); \
    w = u.y; acc[2] += p * __uint_as_float(w << 16); acc[3] += p * __uint_as_float(w & 0xffff0000u); \
    w = u.z; acc[4] += p * __uint_as_float(w << 16); acc[5] += p * __uint_as_float(w & 0xffff0000u); \
    w = u.w; acc[6] += p * __uint_as_float(w << 16); acc[7] += p * __uint_as_float(w & 0xffff0000u);

__global__ __launch_bounds__(256) void gat_aggregate_kernel(
    const int* __restrict__ perm,
    const int* __restrict__ row_ptr, const int* __restrict__ col_idx,
    const float* __restrict__ as_, const float* __restrict__ ad_,
    const __hip_bfloat16* __restrict__ h, const float* __restrict__ b,
    float* __restrict__ out, int N, int do_elu)
{
    const int wave = threadIdx.x >> 6, lane = threadIdx.x & 63;
    const int sub = lane >> 3, q = lane & 7;
    const int idx = blockIdx.x * 32 + wave * 8 + sub;
    if (idx >= N) return;
    const int node = perm[idx];
    const int beg = row_ptr[node], end = row_ptr[node + 1];
    const float ad = ad_[node];          // pre-scaled by log2e
    float acc[8] = {0.f, 0.f, 0.f, 0.f, 0.f, 0.f, 0.f, 0.f};
    float psum = 0.f;

    const char* cbp = (const char*)col_idx;
    const char* abp = (const char*)as_;
    const char* hbp = (const char*)h;
    const unsigned qb = (unsigned)q * 16u;
    unsigned w;

    int i = beg;
    unsigned co = (unsigned)beg * 4u;
    // main loop: 4 edges per window, all loads issued up front
    for (; i + 4 <= end; i += 4, co += 16u) {
        int s0 = *(const int*)(cbp + co);
        int s1 = *(const int*)(cbp + (co + 4u));
        int s2 = *(const int*)(cbp + (co + 8u));
        int s3 = *(const int*)(cbp + (co + 12u));
        float x0 = *(const float*)(abp + ((unsigned)s0 << 2)) + ad;
        float x1 = *(const float*)(abp + ((unsigned)s1 << 2)) + ad;
        float x2 = *(const float*)(abp + ((unsigned)s2 << 2)) + ad;
        float x3 = *(const float*)(abp + ((unsigned)s3 << 2)) + ad;
        uint4 u0 = *(const uint4*)(hbp + (((unsigned)s0 << 7) + qb));
        uint4 u1 = *(const uint4*)(hbp + (((unsigned)s1 << 7) + qb));
        uint4 u2 = *(const uint4*)(hbp + (((unsigned)s2 << 7) + qb));
        uint4 u3 = *(const uint4*)(hbp + (((unsigned)s3 << 7) + qb));
        x0 = fmaxf(x0, NEG_SLOPE * x0);
        x1 = fmaxf(x1, NEG_SLOPE * x1);
        x2 = fmaxf(x2, NEG_SLOPE * x2);
        x3 = fmaxf(x3, NEG_SLOPE * x3);
        float p0 = __builtin_amdgcn_exp2f(x0);
        float p1 = __builtin_amdgcn_exp2f(x1);
        float p2 = __builtin_amdgcn_exp2f(x2);
        float p3 = __builtin_amdgcn_exp2f(x3);
        psum += (p0 + p1) + (p2 + p3);
        ACC8(u0, p0)
        ACC8(u1, p1)
        ACC8(u2, p2)
        ACC8(u3, p3)
    }
    // tail: <=3 masked single-edge steps (degree-sorted -> subs exit together)
    for (; i < end; ++i, co += 4u) {
        int s0 = *(const int*)(cbp + co);
        float x0 = *(const float*)(abp + ((unsigned)s0 << 2)) + ad;
        uint4 u0 = *(const uint4*)(hbp + (((unsigned)s0 << 7) + qb));
        x0 = fmaxf(x0, NEG_SLOPE * x0);
        float p0 = __builtin_amdgcn_exp2f(x0);
        psum += p0;
        ACC8(u0, p0)
    }

    const float inv = 1.f / psum;
    const float* bq = b + q * 8;
    float4 b0 = *(const float4*)bq;
    float4 b1 = *(const float4*)(bq + 4);
    float v[8];
    v[0] = acc[0] * inv + b0.x; v[1] = acc[1] * inv + b0.y;
    v[2] = acc[2] * inv + b0.z; v[3] = acc[3] * inv + b0.w;
    v[4] = acc[4] * inv + b1.x; v[5] = acc[5] * inv + b1.y;
    v[6] = acc[6] * inv + b1.z; v[7] = acc[7] * inv + b1.w;
    if (do_elu) {
#pragma unroll
        for (int j = 0; j < 8; ++j)
            v[j] = v[j] > 0.f ? v[j] : (__expf(v[j]) - 1.f);
    }
    float* op = out + (size_t)node * 64 + q * 8;
    ((float4*)op)[0] = make_float4(v[0], v[1], v[2], v[3]);
    ((float4*)op)[1] = make_float4(v[4], v[5], v[6], v[7]);
}

// logits[n][c] = x[n]·cW[:,c] + cb[c]
__global__ __launch_bounds__(256) void classifier_kernel(
    const float* __restrict__ x, const float* __restrict__ cw,
    const float* __restrict__ cb, float* __restrict__ out, int N)
{
    int i = blockIdx.x * blockDim.x + threadIdx.x;
    if (i >= N * 16) return;
    int n = i >> 4, c = i & 15;
    const float4* xr = (const float4*)(x + (size_t)n * 64);
    float acc = cb[c];
#pragma unroll
    for (int j4 = 0; j4 < 16; ++j4) {
        float4 xv = xr[j4];
        acc += xv.x * cw[(j4 * 4 + 0) * 16 + c];
        acc += xv.y * cw[(j4 * 4 + 1) * 16 + c];
        acc += xv.z * cw[(j4 * 4 + 2) * 16 + c];
        acc += xv.w * cw[(j4 * 4 + 3) * 16 + c];
    }
    out[i] = acc;
}

extern "C" void kernel_launch(void* const* d_in, const int* in_sizes, int n_in,
                              void* d_out, int out_size, void* d_ws, size_t ws_size,
                              hipStream_t stream)
{
    const float* X    = (const float*)d_in[0];
    const int*   adj  = (const int*)d_in[1];
    const float* W1   = (const float*)d_in[2];
    const float* a_s1 = (const float*)d_in[3];
    const float* a_d1 = (const float*)d_in[4];
    const float* b1   = (const float*)d_in[5];
    const float* W2   = (const float*)d_in[6];
    const float* a_s2 = (const float*)d_in[7];
    const float* a_d2 = (const float*)d_in[8];
    const float* b2   = (const float*)d_in[9];
    const float* cW   = (const float*)d_in[10];
    const float* cb   = (const float*)d_in[11];

    const int N   = in_sizes[0] / 128;
    const int E   = in_sizes[1] / 2;
    const int ET  = E + N;
    const int R   = (ET + CH - 1) / CH;           // partition rounds
    const int NBK = (N + BW - 1) >> BSH;          // buckets (<=256)

    __hip_bfloat16* A = (__hip_bfloat16*)d_ws;        // h (bf16), N*64
    float* B       = (float*)(A + (size_t)N * 64);    // layer1 x, N*64 f32
    float* asb     = B + (size_t)N * 64;              // N
    float* adb     = asb + N;                         // N
    int*   row_ptr = (int*)(adb + N);                 // N+1
    int*   col_idx = row_ptr + (N + 1);               // ET
    int*   pbuf    = col_idx + ET;                    // ET
    int*   H       = pbuf + ET;                       // R*NBK
    int*   S2      = H + R * NBK;                     // R*NBK
    int*   tot     = S2 + R * NBK;                    // NBK
    int*   base    = tot + NBK;                       // NBK
    int*   perm    = base + NBK;                      // N
    int*   gh      = perm + N;                        // 256
    int*   gcur    = gh + 256;                        // 256

    // W fragment buffers alias pbuf (dead after csr_build; preps run after it)
    uintptr_t wp = ((uintptr_t)pbuf + 15) & ~(uintptr_t)15;
    unsigned short* wf1 = (unsigned short*)wp;        // 128*64 ushort = 16KB
    unsigned short* wf2 = wf1 + 128 * 64;             // 64*64 ushort = 8KB

    const int T = 256;
    const int aggBlocks  = (N + 31) / 32;
    const int nChunks    = (N + 63) / 64;
    const int gemmBlocks = nChunks < 512 ? nChunks : 512;

    // ---- radix CSR build (once, reused by both layers) ----
    bucket_hist_kernel<<<PGRID, T, 0, stream>>>(adj, H, E, N, R, NBK);
    scan_rounds_kernel<<<NBK, T, 0, stream>>>(H, S2, tot, R, NBK);
    scan_tot_kernel<<<1, T, 0, stream>>>(tot, base, NBK, gh);
    partition_kernel<<<PGRID, T, 0, stream>>>(adj, S2, base, pbuf, E, N, R, NBK);
    csr_build_kernel<<<NBK, T, 0, stream>>>(base, tot, pbuf, row_ptr, col_idx, E, N, NBK);

    // ---- degree-binned node permutation (uniform-degree waves for agg) ----
    deg_hist_kernel<<<128, T, 0, stream>>>(row_ptr, gh, N);
    deg_scan_kernel<<<1, T, 0, stream>>>(gh, gcur);
    deg_scatter_kernel<<<(N + 2047) / 2048, T, 0, stream>>>(row_ptr, gcur, perm, N);

    // ---- pack W fragments (after csr_build: pbuf space is dead now) ----
    prep_wfrag_kernel<<<(128 * 64 + 255) / 256, T, 0, stream>>>(W1, wf1, 128);
    prep_wfrag_kernel<<<(64 * 64 + 255) / 256, T, 0, stream>>>(W2, wf2, 64);

    // ---- layer 1 ----
    gemm_alpha_mfma<128><<<gemmBlocks, T, 0, stream>>>(
        X, wf1, a_s1, a_d1, A, asb, adb, N, nChunks);
    gat_aggregate_kernel<<<aggBlocks, T, 0, stream>>>(
        perm, row_ptr, col_idx, asb, adb, A, b1, B, N, 1);

    // ---- layer 2 (x written straight into d_out tail) ----
    float* out  = (float*)d_out;
    float* xout = out + (size_t)N * 16;
    gemm_alpha_mfma<64><<<gemmBlocks, T, 0, stream>>>(
        B, wf2, a_s2, a_d2, A, asb, adb, N, nChunks);
    gat_aggregate_kernel<<<aggBlocks, T, 0, stream>>>(
        perm, row_ptr, col_idx, asb, adb, A, b2, xout, N, 0);

    // ---- classifier ----
    classifier_kernel<<<(N * 16 + T - 1) / T, T, 0, stream>>>(
        xout, cW, cb, out, N);
}